// Round 6
// baseline (183.245 us; speedup 1.0000x reference)
//
#include <hip/hip_runtime.h>

#define DT (1.0f/60.0f)
#define G_ACC 9.81f
#define RHO 1.225f
#define CD_ 0.47f
#define NU 0.001f

__device__ __forceinline__ float softplus_f(float x) {
    return log1pf(expf(-fabsf(x))) + fmaxf(x, 0.0f);
}

// readlane: lane index is wave-uniform (q*16+jj, q uniform per wave)
#define RL(v, l) __int_as_float(__builtin_amdgcn_readlane(__float_as_int(v), (l)))

// DPP x-shifts within 16-lane rows (x = lane&15). bound_ctrl=1 -> 0 at row
// edges = exactly the conv zero padding.
__device__ __forceinline__ float dpp_xm(float v) { // value from x-1, 0 at x==0
    return __int_as_float(__builtin_amdgcn_update_dpp(0, __float_as_int(v), 0x111, 0xf, 0xf, true));
}
__device__ __forceinline__ float dpp_xp(float v) { // value from x+1, 0 at x==15
    return __int_as_float(__builtin_amdgcn_update_dpp(0, __float_as_int(v), 0x101, 0xf, 0xf, true));
}

// ---------------------------------------------------------------------------
// Fluid body. USE_WS=true: ch0/ch1 de-meaned results staged to d_ws
// ([b][c][z][t], stride-1 coalesced, 16MB total) -- a CONTROLLED spill of
// cold data, once per channel, outside all loops. Keeps the conv body at
// R4's measured 92 VGPR (register-stash variants measured 152-176 VGPR ->
// 3 blocks/CU; the allocator's response to 32 persistent regs is +72).
// ws write->read ordering: the __syncthreads between channels drain vmcnt.
// USE_WS=false: R5's register-stash fallback (when ws_size < 16MB).
// ---------------------------------------------------------------------------
template<bool USE_WS>
__device__ __forceinline__ void fluid_body(
    int b, int t, float* smem,
    const float* __restrict__ fluid, const float* __restrict__ conv_w,
    float* __restrict__ ws, float* __restrict__ out)
{
    const int x  = t & 15, y = t >> 4, wv = t >> 6;
    float* u   = smem;           // col*17 + z, stride 17 -> conflict-free
    float* wch = smem + 4352;
    float* red = smem + 4380;
    const int lb = t*17;

    const float mm = (y > 0)  ? 1.f : 0.f;
    const float pm = (y < 15) ? 1.f : 0.f;
    const float xm = (x > 0)  ? 1.f : 0.f;
    const float xp = (x < 15) ? 1.f : 0.f;
    const int   cm = (y > 0)  ? lb - 272 : lb;   // 16*17
    const int   cp = (y < 15) ? lb + 272 : lb;

    const float wgt[4] = {1.f, 2.f, 2.f, 1.f};
    const float hs[3]  = {DT*0.5f, DT*0.5f, DT};

    float raw0[16], raw1[16];    // only live in !USE_WS mode (dead-stripped)

    #define ACC3(c, wi) { \
        float w0_ = W[wi], w1_ = W[9+(wi)], w2_ = W[18+(wi)]; \
        _Pragma("unroll") for (int z = 0; z < 16; ++z) o[z] += w1_ * (c)[z]; \
        _Pragma("unroll") for (int z = 1; z < 16; ++z) o[z] += w0_ * (c)[z-1]; \
        _Pragma("unroll") for (int z = 0; z < 15; ++z) o[z] += w2_ * (c)[z+1]; }

    for (int ch = 0; ch < 3; ++ch) {
        // Safe to overwrite u/wch: all reads of the previous channel's
        // state/weights complete before its trailing barrier pair.
        if (t < 27) wch[t] = conv_w[ch*27 + t];
        const float* fb = fluid + (size_t)b*12288 + 3*t + ch;
        float base[16], acc[16];
        #pragma unroll
        for (int z = 0; z < 16; ++z) {
            float v = fb[z*768];
            base[z] = v; acc[z] = 0.f; u[lb + z] = v;
        }
        __syncthreads();

        // valid-tap weight sums for mean folding: conv(w-mean) = conv(w) - mean*S
        float Sdz[3];
        #pragma unroll
        for (int dz = 0; dz < 3; ++dz) {
            float a0 = wch[dz*9+0]*xm + wch[dz*9+1] + wch[dz*9+2]*xp;   // dy=-1
            float a1 = wch[dz*9+3]*xm + wch[dz*9+4] + wch[dz*9+5]*xp;   // dy= 0
            float a2 = wch[dz*9+6]*xm + wch[dz*9+7] + wch[dz*9+8]*xp;   // dy=+1
            Sdz[dz] = mm*a0 + a1 + pm*a2;
        }
        const float SzLo  = Sdz[1] + Sdz[2];            // z == 0
        const float SzMid = Sdz[0] + Sdz[1] + Sdz[2];   // 0 < z < 15
        const float SzHi  = Sdz[0] + Sdz[1];            // z == 15
        const float* W = wch;
        float mean = 0.f;

        for (int s = 0; s < 4; ++s) {
            float o[16];
            #pragma unroll
            for (int z = 0; z < 16; ++z) o[z] = 0.f;

            {   // dy = 0 (own column from LDS)
                float c0[16], cl[16], cr[16];
                #pragma unroll
                for (int z = 0; z < 16; ++z) c0[z] = u[lb + z];
                #pragma unroll
                for (int z = 0; z < 16; ++z) { cl[z] = dpp_xm(c0[z]); cr[z] = dpp_xp(c0[z]); }
                ACC3(c0, 4); ACC3(cl, 3); ACC3(cr, 5);
            }
            {   // dy = -1
                float c0[16], cl[16], cr[16];
                #pragma unroll
                for (int z = 0; z < 16; ++z) c0[z] = u[cm + z] * mm;
                #pragma unroll
                for (int z = 0; z < 16; ++z) { cl[z] = dpp_xm(c0[z]); cr[z] = dpp_xp(c0[z]); }
                ACC3(c0, 1); ACC3(cl, 0); ACC3(cr, 2);
            }
            {   // dy = +1
                float c0[16], cl[16], cr[16];
                #pragma unroll
                for (int z = 0; z < 16; ++z) c0[z] = u[cp + z] * pm;
                #pragma unroll
                for (int z = 0; z < 16; ++z) { cl[z] = dpp_xm(c0[z]); cr[z] = dpp_xp(c0[z]); }
                ACC3(c0, 7); ACC3(cl, 6); ACC3(cr, 8);
            }

            float w = wgt[s];
            if (s < 3) {
                float h = hs[s], ps = 0.f, wn[16];
                #pragma unroll
                for (int z = 0; z < 16; ++z) {
                    float Sz = (z == 0) ? SzLo : ((z == 15) ? SzHi : SzMid);
                    float k = NU * (o[z] - mean * Sz);
                    acc[z] += w * k;
                    wn[z] = base[z] + h * k;
                    ps += wn[z];
                }
                #pragma unroll
                for (int off = 32; off > 0; off >>= 1) ps += __shfl_xor(ps, off, 64);
                __syncthreads();            // WAR: all conv reads of state s done
                #pragma unroll
                for (int z = 0; z < 16; ++z) u[lb + z] = wn[z];
                if ((t & 63) == 0) red[wv] = ps;
                __syncthreads();            // writes + red visible (drains vmcnt)
                mean = (red[0] + red[1] + red[2] + red[3]) * (1.0f/4096.0f);
            } else {
                #pragma unroll
                for (int z = 0; z < 16; ++z) {
                    float Sz = (z == 0) ? SzLo : ((z == 15) ? SzHi : SzMid);
                    acc[z] += w * NU * (o[z] - mean * Sz);
                }
            }
        }

        // final per-channel mean from sums
        float ps = 0.f;
        #pragma unroll
        for (int z = 0; z < 16; ++z) ps += base[z] + (DT/6.0f)*acc[z];
        #pragma unroll
        for (int off = 32; off > 0; off >>= 1) ps += __shfl_xor(ps, off, 64);
        __syncthreads();                    // WAR on red vs stage mean reads
        if ((t & 63) == 0) red[wv] = ps;
        __syncthreads();
        float mn = (red[0] + red[1] + red[2] + red[3]) * (1.0f/4096.0f);

        if (ch == 0) {
            if constexpr (USE_WS) {
                float* wsb = ws + (size_t)b*8192 + t;      // [b][0][z][t]
                #pragma unroll
                for (int z = 0; z < 16; ++z) wsb[z*256] = base[z] + (DT/6.0f)*acc[z] - mn;
            } else {
                #pragma unroll
                for (int z = 0; z < 16; ++z) raw0[z] = base[z] + (DT/6.0f)*acc[z] - mn;
            }
        } else if (ch == 1) {
            if constexpr (USE_WS) {
                float* wsb = ws + (size_t)b*8192 + 4096 + t;  // [b][1][z][t]
                #pragma unroll
                for (int z = 0; z < 16; ++z) wsb[z*256] = base[z] + (DT/6.0f)*acc[z] - mn;
            } else {
                #pragma unroll
                for (int z = 0; z < 16; ++z) raw1[z] = base[z] + (DT/6.0f)*acc[z] - mn;
            }
        } else {
            // single coalesced float3 write pass: thread t writes 12
            // contiguous bytes per z -> full-line writebacks, no RFO.
            float* ob = out + (size_t)b*13313 + 1025 + 3*t;
            if constexpr (USE_WS) {
                const float* wsb = ws + (size_t)b*8192 + t;
                #pragma unroll
                for (int z = 0; z < 16; ++z) {
                    ob[z*768 + 0] = wsb[z*256];
                    ob[z*768 + 1] = wsb[4096 + z*256];
                    ob[z*768 + 2] = base[z] + (DT/6.0f)*acc[z] - mn;
                }
            } else {
                #pragma unroll
                for (int z = 0; z < 16; ++z) {
                    ob[z*768 + 0] = raw0[z];
                    ob[z*768 + 1] = raw1[z];
                    ob[z*768 + 2] = base[z] + (DT/6.0f)*acc[z] - mn;
                }
            }
        }
    }
    #undef ACC3
}

// ---------------------------------------------------------------------------
// Particle body (identical to R5; untouched by the staging experiment).
// ---------------------------------------------------------------------------
__device__ __forceinline__ void particle_body(
    int b, int t, float* smem,
    const float* __restrict__ pos, const float* __restrict__ vel,
    const float* __restrict__ rot, const float* __restrict__ omega,
    const float* __restrict__ mass, const float* __restrict__ inertia,
    const float* __restrict__ contacts, const float* __restrict__ energy,
    const float* __restrict__ Fext, const float* __restrict__ tau,
    const float* __restrict__ log_A, const float* __restrict__ log_k,
    const float* __restrict__ log_b, float* __restrict__ out)
{
    const int q = t >> 6;       // j-chunk / wave id
    const int i = t & 63;       // particle id
    #define SF(buf, qq, idx) smem[(buf)*768 + (qq)*192 + (idx)]

    const float* cbase = contacts + (size_t)b*4096 + (size_t)i*64 + q*16;
    float4 cA = ((const float4*)cbase)[0];
    float4 cB = ((const float4*)cbase)[1];
    float4 cC = ((const float4*)cbase)[2];
    float4 cD = ((const float4*)cbase)[3];
    float cj[16] = {cA.x,cA.y,cA.z,cA.w, cB.x,cB.y,cB.z,cB.w,
                    cC.x,cC.y,cC.z,cC.w, cD.x,cD.y,cD.z,cD.w};

    const size_t p3 = ((size_t)b*64 + i)*3;
    const size_t p4 = ((size_t)b*64 + i)*4;
    float bpx=pos[p3],   bpy=pos[p3+1],   bpz=pos[p3+2];
    float bvx=vel[p3],   bvy=vel[p3+1],   bvz=vel[p3+2];
    float brw=rot[p4],   brx=rot[p4+1],   bry=rot[p4+2],  brz=rot[p4+3];
    float box=omega[p3], boy=omega[p3+1], boz=omega[p3+2];
    float m  = mass[(size_t)b*64+i];
    float Ix=inertia[p3], Iy=inertia[p3+1], Iz=inertia[p3+2];
    float Fex=Fext[p3],   Fey=Fext[p3+1],   Fez=Fext[p3+2];
    float tx=tau[p3],     ty=tau[p3+1],     tz=tau[p3+2];
    float Ai = softplus_f(log_A[i]);
    float kc = softplus_f(log_k[0]);
    float bc = softplus_f(log_b[0]);
    float dragc = -0.5f * RHO * CD_ * Ai;
    float invm  = 1.0f / m;
    float iIx = 1.0f/fmaxf(Ix,1e-6f), iIy = 1.0f/fmaxf(Iy,1e-6f), iIz = 1.0f/fmaxf(Iz,1e-6f);

    float cpx=bpx, cpy=bpy, cpz=bpz;
    float cvx=bvx, cvy=bvy, cvz=bvz;
    float crw=brw, crx=brx, cry=bry, crz=brz;
    float cox=box, coy=boy, coz=boz;

    float apx=0,apy=0,apz=0, avx=0,avy=0,avz=0;
    float arw=0,arx=0,ary=0,arz=0, awx=0,awy=0,awz=0;
    float eacc=0.f;
    float k1vx=0,k1vy=0,k1vz=0;

    const float wgt[4] = {1.f, 2.f, 2.f, 1.f};
    const float hs[4]  = {DT*0.5f, DT*0.5f, DT, 0.f};
    const int j0 = q << 4;

    for (int s = 0; s < 4; ++s) {
        float Fcx=0.f, Fcy=0.f, Fcz=0.f;
        #pragma unroll
        for (int jj = 0; jj < 16; ++jj) {
            const int j = j0 + jj;
            float pjx = RL(cpx, j), pjy = RL(cpy, j), pjz = RL(cpz, j);
            float vjx = RL(cvx, j), vjy = RL(cvy, j), vjz = RL(cvz, j);
            float dx = pjx - cpx, dy = pjy - cpy, dz = pjz - cpz;
            float d2 = dx*dx + dy*dy + dz*dz;
            float dist = fmaxf(sqrtf(d2), 1e-6f);
            float pen  = fmaxf(1.0f - dist, 0.0f);
            float coef = kc * pen * __builtin_amdgcn_rcpf(dist);
            float cbj  = bc * cj[jj];
            Fcx += coef*dx + cbj*(vjx - cvx);
            Fcy += coef*dy + cbj*(vjy - cvy);
            Fcz += coef*dz + cbj*(vjz - cvz);
        }
        const int buf = s & 1;
        SF(buf, q, i*3+0) = Fcx;
        SF(buf, q, i*3+1) = Fcy;
        SF(buf, q, i*3+2) = Fcz;
        __syncthreads();
        Fcx = SF(buf,0,i*3+0) + SF(buf,1,i*3+0) + SF(buf,2,i*3+0) + SF(buf,3,i*3+0);
        Fcy = SF(buf,0,i*3+1) + SF(buf,1,i*3+1) + SF(buf,2,i*3+1) + SF(buf,3,i*3+1);
        Fcz = SF(buf,0,i*3+2) + SF(buf,1,i*3+2) + SF(buf,2,i*3+2) + SF(buf,3,i*3+2);

        float vm = fmaxf(sqrtf(cvx*cvx+cvy*cvy+cvz*cvz), 1e-6f);
        float dc = dragc * vm;
        float Fdx = dc*cvx, Fdy = dc*cvy, Fdz = dc*cvz;

        float dvx = (Fex + Fdx + Fcx) * invm;
        float dvy = (Fey + Fdy + Fcy) * invm;
        float dvz = (Fez - m*G_ACC + Fdz + Fcz) * invm;

        float dqw = 0.5f*(-crx*cox - cry*coy - crz*coz);
        float dqx = 0.5f*( crw*cox + cry*coz - crz*coy);
        float dqy = 0.5f*( crw*coy - crx*coz + crz*cox);
        float dqz = 0.5f*( crw*coz + crx*coy - cry*cox);

        float Iox = Ix*cox, Ioy = Iy*coy, Ioz = Iz*coz;
        float cxv = coy*Ioz - coz*Ioy;
        float cyv = coz*Iox - cox*Ioz;
        float czv = cox*Ioy - coy*Iox;
        float dwx = (tx - cxv) * iIx;
        float dwy = (ty - cyv) * iIy;
        float dwz = (tz - czv) * iIz;

        float ei = (Fex+Fdx)*cvx + (Fey+Fdy)*cvy + (Fez+Fdz)*cvz;
        #pragma unroll
        for (int off = 32; off > 0; off >>= 1) ei += __shfl_xor(ei, off, 64);

        float w = wgt[s];
        eacc += w * ei;
        if (s == 0) { k1vx=dvx; k1vy=dvy; k1vz=dvz; }
        apx += w*cvx; apy += w*cvy; apz += w*cvz;
        avx += w*dvx; avy += w*dvy; avz += w*dvz;
        arw += w*dqw; arx += w*dqx; ary += w*dqy; arz += w*dqz;
        awx += w*dwx; awy += w*dwy; awz += w*dwz;

        if (s < 3) {
            float h = hs[s];
            float npx = bpx + h*cvx, npy = bpy + h*cvy, npz = bpz + h*cvz;
            cvx = bvx + h*dvx; cvy = bvy + h*dvy; cvz = bvz + h*dvz;
            cpx = npx; cpy = npy; cpz = npz;
            float qw = brw + h*dqw, qx = brx + h*dqx, qy = bry + h*dqy, qz = brz + h*dqz;
            float iqn = 1.0f / fmaxf(sqrtf(qw*qw+qx*qx+qy*qy+qz*qz), 1e-12f);
            crw = qw*iqn; crx = qx*iqn; cry = qy*iqn; crz = qz*iqn;
            cox = box + h*dwx; coy = boy + h*dwy; coz = boz + h*dwz;
        }
    }

    if (q == 0) {
        const float s6 = DT / 6.0f;
        float* ob = out + (size_t)b * 13313;
        ob[      i*3+0] = bpx + s6*apx;  ob[      i*3+1] = bpy + s6*apy;  ob[      i*3+2] = bpz + s6*apz;
        ob[192 + i*3+0] = bvx + s6*avx;  ob[192 + i*3+1] = bvy + s6*avy;  ob[192 + i*3+2] = bvz + s6*avz;
        {
            float qw=brw+s6*arw, qx=brx+s6*arx, qy=bry+s6*ary, qz=brz+s6*arz;
            float iq = 1.0f / fmaxf(sqrtf(qw*qw+qx*qx+qy*qy+qz*qz), 1e-12f);
            ob[384 + i*4+0]=qw*iq; ob[384 + i*4+1]=qx*iq; ob[384 + i*4+2]=qy*iq; ob[384 + i*4+3]=qz*iq;
        }
        ob[640 + i*3+0] = box + s6*awx;  ob[640 + i*3+1] = boy + s6*awy;  ob[640 + i*3+2] = boz + s6*awz;
        ob[832 + i*3+0] = Fex + m*k1vx;  ob[832 + i*3+1] = Fey + m*k1vy;  ob[832 + i*3+2] = Fez + m*k1vz;
        if (i == 0) ob[1024] = energy[b] + s6*eacc;
    }
    #undef SF
}

// ---------------------------------------------------------------------------
// grid = 1024 x 256. blocks [0,512): fluid (b = blk); [512,1024): particle.
// ---------------------------------------------------------------------------
__global__ __launch_bounds__(256) void fused_kernel_ws(
    const float* __restrict__ pos, const float* __restrict__ vel,
    const float* __restrict__ rot, const float* __restrict__ omega,
    const float* __restrict__ mass, const float* __restrict__ inertia,
    const float* __restrict__ contacts, const float* __restrict__ energy,
    const float* __restrict__ fluid, const float* __restrict__ Fext,
    const float* __restrict__ tau, const float* __restrict__ log_A,
    const float* __restrict__ log_k, const float* __restrict__ log_b,
    const float* __restrict__ conv_w, float* __restrict__ out,
    float* __restrict__ ws)
{
    __shared__ float smem[4384];
    const int t = threadIdx.x;
    if (blockIdx.x < 512) {
        fluid_body<true>(blockIdx.x, t, smem, fluid, conv_w, ws, out);
        return;
    }
    particle_body(blockIdx.x - 512, t, smem, pos, vel, rot, omega, mass,
                  inertia, contacts, energy, Fext, tau, log_A, log_k, log_b, out);
}

__global__ __launch_bounds__(256) void fused_kernel_reg(
    const float* __restrict__ pos, const float* __restrict__ vel,
    const float* __restrict__ rot, const float* __restrict__ omega,
    const float* __restrict__ mass, const float* __restrict__ inertia,
    const float* __restrict__ contacts, const float* __restrict__ energy,
    const float* __restrict__ fluid, const float* __restrict__ Fext,
    const float* __restrict__ tau, const float* __restrict__ log_A,
    const float* __restrict__ log_k, const float* __restrict__ log_b,
    const float* __restrict__ conv_w, float* __restrict__ out)
{
    __shared__ float smem[4384];
    const int t = threadIdx.x;
    if (blockIdx.x < 512) {
        fluid_body<false>(blockIdx.x, t, smem, fluid, conv_w, nullptr, out);
        return;
    }
    particle_body(blockIdx.x - 512, t, smem, pos, vel, rot, omega, mass,
                  inertia, contacts, energy, Fext, tau, log_A, log_k, log_b, out);
}

extern "C" void kernel_launch(void* const* d_in, const int* in_sizes, int n_in,
                              void* d_out, int out_size, void* d_ws, size_t ws_size,
                              hipStream_t stream) {
    const float* pos      = (const float*)d_in[0];
    const float* vel      = (const float*)d_in[1];
    const float* rot      = (const float*)d_in[2];
    const float* omega    = (const float*)d_in[3];
    const float* mass     = (const float*)d_in[4];
    const float* inertia  = (const float*)d_in[5];
    const float* contacts = (const float*)d_in[6];
    const float* energy   = (const float*)d_in[7];
    const float* fluid_v  = (const float*)d_in[8];
    const float* Fext     = (const float*)d_in[9];
    const float* tau      = (const float*)d_in[10];
    const float* log_A    = (const float*)d_in[11];
    const float* log_k    = (const float*)d_in[12];
    const float* log_b    = (const float*)d_in[13];
    const float* conv_w   = (const float*)d_in[14];
    float* out = (float*)d_out;

    const size_t ws_needed = (size_t)512 * 8192 * sizeof(float);   // 16 MB
    if (d_ws != nullptr && ws_size >= ws_needed) {
        fused_kernel_ws<<<dim3(1024), dim3(256), 0, stream>>>(
            pos, vel, rot, omega, mass, inertia, contacts, energy, fluid_v,
            Fext, tau, log_A, log_k, log_b, conv_w, out, (float*)d_ws);
    } else {
        fused_kernel_reg<<<dim3(1024), dim3(256), 0, stream>>>(
            pos, vel, rot, omega, mass, inertia, contacts, energy, fluid_v,
            Fext, tau, log_A, log_k, log_b, conv_w, out);
    }
}

// Round 7
// 160.996 us; speedup vs baseline: 1.1382x; 1.1382x over previous
//
#include <hip/hip_runtime.h>

#define DT (1.0f/60.0f)
#define G_ACC 9.81f
#define RHO 1.225f
#define CD_ 0.47f
#define NU 0.001f

__device__ __forceinline__ float softplus_f(float x) {
    return log1pf(expf(-fabsf(x))) + fmaxf(x, 0.0f);
}

// readlane: lane index is wave-uniform (q*16+jj, q uniform per wave)
#define RL(v, l) __int_as_float(__builtin_amdgcn_readlane(__float_as_int(v), (l)))

// DPP x-shifts within 16-lane rows (x = lane&15). bound_ctrl=1 -> 0 at row
// edges = exactly the conv zero padding.
__device__ __forceinline__ float dpp_xm(float v) { // value from x-1, 0 at x==0
    return __int_as_float(__builtin_amdgcn_update_dpp(0, __float_as_int(v), 0x111, 0xf, 0xf, true));
}
__device__ __forceinline__ float dpp_xp(float v) { // value from x+1, 0 at x==15
    return __int_as_float(__builtin_amdgcn_update_dpp(0, __float_as_int(v), 0x101, 0xf, 0xf, true));
}

// ---------------------------------------------------------------------------
// Kernel A. grid = 1024 x 256 threads.
//   blocks [0,512):    fluid, b = blk. ONE block per batch, 3 channels
//                      sequential (R4's exact 92-VGPR body). Each channel's
//                      de-meaned result is written STRIDE-1 into out's fluid
//                      region at a temporary PLANAR layout [ch][z][t]:
//                      clean full-line writes, no RFO, no persistent regs,
//                      no ws. Kernel B permutes planar -> interleaved.
//   blocks [512,1024): particle, b = blk-512 (writes final layout directly).
// Register discipline (R1/R3/R5/R6 lessons): any attempt to hold the
// channel stash in registers costs 152-192 VGPR -> 3 blocks/CU. R4's body
// with a uniform 16-store epilogue measured 92 VGPR -> 5 blocks/CU.
// ---------------------------------------------------------------------------
__global__ __launch_bounds__(256) void fused_kernel(
    const float* __restrict__ pos, const float* __restrict__ vel,
    const float* __restrict__ rot, const float* __restrict__ omega,
    const float* __restrict__ mass, const float* __restrict__ inertia,
    const float* __restrict__ contacts, const float* __restrict__ energy,
    const float* __restrict__ fluid, const float* __restrict__ Fext,
    const float* __restrict__ tau, const float* __restrict__ log_A,
    const float* __restrict__ log_k, const float* __restrict__ log_b,
    const float* __restrict__ conv_w, float* __restrict__ out)
{
    __shared__ float smem[4384];     // fluid: u[4352]+wch[27]+red[4]; particle: sF[1536]
    const int t = threadIdx.x;

    if (blockIdx.x < 512) {
        // ================= FLUID =================
        const int b  = blockIdx.x;
        const int x  = t & 15, y = t >> 4, wv = t >> 6;
        float* u   = smem;           // col*17 + z, stride 17 -> conflict-free
        float* wch = smem + 4352;
        float* red = smem + 4380;
        const int lb = t*17;

        const float mm = (y > 0)  ? 1.f : 0.f;
        const float pm = (y < 15) ? 1.f : 0.f;
        const float xm = (x > 0)  ? 1.f : 0.f;
        const float xp = (x < 15) ? 1.f : 0.f;
        const int   cm = (y > 0)  ? lb - 272 : lb;   // 16*17
        const int   cp = (y < 15) ? lb + 272 : lb;

        const float wgt[4] = {1.f, 2.f, 2.f, 1.f};
        const float hs[3]  = {DT*0.5f, DT*0.5f, DT};

        #define ACC3(c, wi) { \
            float w0_ = W[wi], w1_ = W[9+(wi)], w2_ = W[18+(wi)]; \
            _Pragma("unroll") for (int z = 0; z < 16; ++z) o[z] += w1_ * (c)[z]; \
            _Pragma("unroll") for (int z = 1; z < 16; ++z) o[z] += w0_ * (c)[z-1]; \
            _Pragma("unroll") for (int z = 0; z < 15; ++z) o[z] += w2_ * (c)[z+1]; }

        for (int ch = 0; ch < 3; ++ch) {
            // Safe to overwrite u/wch: all reads of the previous channel's
            // state/weights complete before its trailing barrier pair.
            if (t < 27) wch[t] = conv_w[ch*27 + t];
            const float* fb = fluid + (size_t)b*12288 + 3*t + ch;
            float base[16], acc[16];
            #pragma unroll
            for (int z = 0; z < 16; ++z) {
                float v = fb[z*768];
                base[z] = v; acc[z] = 0.f; u[lb + z] = v;
            }
            __syncthreads();

            // valid-tap weight sums for mean folding: conv(w-mean) = conv(w) - mean*S
            float Sdz[3];
            #pragma unroll
            for (int dz = 0; dz < 3; ++dz) {
                float a0 = wch[dz*9+0]*xm + wch[dz*9+1] + wch[dz*9+2]*xp;   // dy=-1
                float a1 = wch[dz*9+3]*xm + wch[dz*9+4] + wch[dz*9+5]*xp;   // dy= 0
                float a2 = wch[dz*9+6]*xm + wch[dz*9+7] + wch[dz*9+8]*xp;   // dy=+1
                Sdz[dz] = mm*a0 + a1 + pm*a2;
            }
            const float SzLo  = Sdz[1] + Sdz[2];            // z == 0
            const float SzMid = Sdz[0] + Sdz[1] + Sdz[2];   // 0 < z < 15
            const float SzHi  = Sdz[0] + Sdz[1];            // z == 15
            const float* W = wch;
            float mean = 0.f;

            for (int s = 0; s < 4; ++s) {
                float o[16];
                #pragma unroll
                for (int z = 0; z < 16; ++z) o[z] = 0.f;

                {   // dy = 0 (own column from LDS)
                    float c0[16], cl[16], cr[16];
                    #pragma unroll
                    for (int z = 0; z < 16; ++z) c0[z] = u[lb + z];
                    #pragma unroll
                    for (int z = 0; z < 16; ++z) { cl[z] = dpp_xm(c0[z]); cr[z] = dpp_xp(c0[z]); }
                    ACC3(c0, 4); ACC3(cl, 3); ACC3(cr, 5);
                }
                {   // dy = -1
                    float c0[16], cl[16], cr[16];
                    #pragma unroll
                    for (int z = 0; z < 16; ++z) c0[z] = u[cm + z] * mm;
                    #pragma unroll
                    for (int z = 0; z < 16; ++z) { cl[z] = dpp_xm(c0[z]); cr[z] = dpp_xp(c0[z]); }
                    ACC3(c0, 1); ACC3(cl, 0); ACC3(cr, 2);
                }
                {   // dy = +1
                    float c0[16], cl[16], cr[16];
                    #pragma unroll
                    for (int z = 0; z < 16; ++z) c0[z] = u[cp + z] * pm;
                    #pragma unroll
                    for (int z = 0; z < 16; ++z) { cl[z] = dpp_xm(c0[z]); cr[z] = dpp_xp(c0[z]); }
                    ACC3(c0, 7); ACC3(cl, 6); ACC3(cr, 8);
                }

                float w = wgt[s];
                if (s < 3) {
                    float h = hs[s], ps = 0.f, wn[16];
                    #pragma unroll
                    for (int z = 0; z < 16; ++z) {
                        float Sz = (z == 0) ? SzLo : ((z == 15) ? SzHi : SzMid);
                        float k = NU * (o[z] - mean * Sz);
                        acc[z] += w * k;
                        wn[z] = base[z] + h * k;
                        ps += wn[z];
                    }
                    #pragma unroll
                    for (int off = 32; off > 0; off >>= 1) ps += __shfl_xor(ps, off, 64);
                    __syncthreads();            // WAR: all conv reads of state s done
                    #pragma unroll
                    for (int z = 0; z < 16; ++z) u[lb + z] = wn[z];
                    if ((t & 63) == 0) red[wv] = ps;
                    __syncthreads();            // writes + red visible
                    mean = (red[0] + red[1] + red[2] + red[3]) * (1.0f/4096.0f);
                } else {
                    #pragma unroll
                    for (int z = 0; z < 16; ++z) {
                        float Sz = (z == 0) ? SzLo : ((z == 15) ? SzHi : SzMid);
                        acc[z] += w * NU * (o[z] - mean * Sz);
                    }
                }
            }

            // final per-channel mean from sums
            float ps = 0.f;
            #pragma unroll
            for (int z = 0; z < 16; ++z) ps += base[z] + (DT/6.0f)*acc[z];
            #pragma unroll
            for (int off = 32; off > 0; off >>= 1) ps += __shfl_xor(ps, off, 64);
            __syncthreads();                    // WAR on red vs stage mean reads
            if ((t & 63) == 0) red[wv] = ps;
            __syncthreads();
            float mn = (red[0] + red[1] + red[2] + red[3]) * (1.0f/4096.0f);

            // PLANAR write: [ch][z][t] inside out's fluid region, stride-1
            // across t -> clean full-line writebacks, uniform per channel.
            float* ob = out + (size_t)b*13313 + 1025 + ch*4096 + t;
            #pragma unroll
            for (int z = 0; z < 16; ++z) ob[z*256] = base[z] + (DT/6.0f)*acc[z] - mn;
        }
        #undef ACC3
        return;
    }

    // ================= PARTICLE =================
    const int b = blockIdx.x - 512;
    const int q = t >> 6;       // j-chunk / wave id
    const int i = t & 63;       // particle id
    #define SF(buf, qq, idx) smem[(buf)*768 + (qq)*192 + (idx)]

    const float* cbase = contacts + (size_t)b*4096 + (size_t)i*64 + q*16;
    float4 cA = ((const float4*)cbase)[0];
    float4 cB = ((const float4*)cbase)[1];
    float4 cC = ((const float4*)cbase)[2];
    float4 cD = ((const float4*)cbase)[3];
    float cj[16] = {cA.x,cA.y,cA.z,cA.w, cB.x,cB.y,cB.z,cB.w,
                    cC.x,cC.y,cC.z,cC.w, cD.x,cD.y,cD.z,cD.w};

    const size_t p3 = ((size_t)b*64 + i)*3;
    const size_t p4 = ((size_t)b*64 + i)*4;
    float bpx=pos[p3],   bpy=pos[p3+1],   bpz=pos[p3+2];
    float bvx=vel[p3],   bvy=vel[p3+1],   bvz=vel[p3+2];
    float brw=rot[p4],   brx=rot[p4+1],   bry=rot[p4+2],  brz=rot[p4+3];
    float box=omega[p3], boy=omega[p3+1], boz=omega[p3+2];
    float m  = mass[(size_t)b*64+i];
    float Ix=inertia[p3], Iy=inertia[p3+1], Iz=inertia[p3+2];
    float Fex=Fext[p3],   Fey=Fext[p3+1],   Fez=Fext[p3+2];
    float tx=tau[p3],     ty=tau[p3+1],     tz=tau[p3+2];
    float Ai = softplus_f(log_A[i]);
    float kc = softplus_f(log_k[0]);
    float bc = softplus_f(log_b[0]);
    float dragc = -0.5f * RHO * CD_ * Ai;
    float invm  = 1.0f / m;
    float iIx = 1.0f/fmaxf(Ix,1e-6f), iIy = 1.0f/fmaxf(Iy,1e-6f), iIz = 1.0f/fmaxf(Iz,1e-6f);

    float cpx=bpx, cpy=bpy, cpz=bpz;
    float cvx=bvx, cvy=bvy, cvz=bvz;
    float crw=brw, crx=brx, cry=bry, crz=brz;
    float cox=box, coy=boy, coz=boz;

    float apx=0,apy=0,apz=0, avx=0,avy=0,avz=0;
    float arw=0,arx=0,ary=0,arz=0, awx=0,awy=0,awz=0;
    float eacc=0.f;
    float k1vx=0,k1vy=0,k1vz=0;

    const float wgt[4] = {1.f, 2.f, 2.f, 1.f};
    const float hs[4]  = {DT*0.5f, DT*0.5f, DT, 0.f};
    const int j0 = q << 4;

    for (int s = 0; s < 4; ++s) {
        float Fcx=0.f, Fcy=0.f, Fcz=0.f;
        #pragma unroll
        for (int jj = 0; jj < 16; ++jj) {
            const int j = j0 + jj;
            float pjx = RL(cpx, j), pjy = RL(cpy, j), pjz = RL(cpz, j);
            float vjx = RL(cvx, j), vjy = RL(cvy, j), vjz = RL(cvz, j);
            float dx = pjx - cpx, dy = pjy - cpy, dz = pjz - cpz;
            float d2 = dx*dx + dy*dy + dz*dz;
            float dist = fmaxf(sqrtf(d2), 1e-6f);
            float pen  = fmaxf(1.0f - dist, 0.0f);
            float coef = kc * pen * __builtin_amdgcn_rcpf(dist);
            float cbj  = bc * cj[jj];
            Fcx += coef*dx + cbj*(vjx - cvx);
            Fcy += coef*dy + cbj*(vjy - cvy);
            Fcz += coef*dz + cbj*(vjz - cvz);
        }
        const int buf = s & 1;
        SF(buf, q, i*3+0) = Fcx;
        SF(buf, q, i*3+1) = Fcy;
        SF(buf, q, i*3+2) = Fcz;
        __syncthreads();
        Fcx = SF(buf,0,i*3+0) + SF(buf,1,i*3+0) + SF(buf,2,i*3+0) + SF(buf,3,i*3+0);
        Fcy = SF(buf,0,i*3+1) + SF(buf,1,i*3+1) + SF(buf,2,i*3+1) + SF(buf,3,i*3+1);
        Fcz = SF(buf,0,i*3+2) + SF(buf,1,i*3+2) + SF(buf,2,i*3+2) + SF(buf,3,i*3+2);

        float vm = fmaxf(sqrtf(cvx*cvx+cvy*cvy+cvz*cvz), 1e-6f);
        float dc = dragc * vm;
        float Fdx = dc*cvx, Fdy = dc*cvy, Fdz = dc*cvz;

        float dvx = (Fex + Fdx + Fcx) * invm;
        float dvy = (Fey + Fdy + Fcy) * invm;
        float dvz = (Fez - m*G_ACC + Fdz + Fcz) * invm;

        float dqw = 0.5f*(-crx*cox - cry*coy - crz*coz);
        float dqx = 0.5f*( crw*cox + cry*coz - crz*coy);
        float dqy = 0.5f*( crw*coy - crx*coz + crz*cox);
        float dqz = 0.5f*( crw*coz + crx*coy - cry*cox);

        float Iox = Ix*cox, Ioy = Iy*coy, Ioz = Iz*coz;
        float cxv = coy*Ioz - coz*Ioy;
        float cyv = coz*Iox - cox*Ioz;
        float czv = cox*Ioy - coy*Iox;
        float dwx = (tx - cxv) * iIx;
        float dwy = (ty - cyv) * iIy;
        float dwz = (tz - czv) * iIz;

        float ei = (Fex+Fdx)*cvx + (Fey+Fdy)*cvy + (Fez+Fdz)*cvz;
        #pragma unroll
        for (int off = 32; off > 0; off >>= 1) ei += __shfl_xor(ei, off, 64);

        float w = wgt[s];
        eacc += w * ei;
        if (s == 0) { k1vx=dvx; k1vy=dvy; k1vz=dvz; }
        apx += w*cvx; apy += w*cvy; apz += w*cvz;
        avx += w*dvx; avy += w*dvy; avz += w*dvz;
        arw += w*dqw; arx += w*dqx; ary += w*dqy; arz += w*dqz;
        awx += w*dwx; awy += w*dwy; awz += w*dwz;

        if (s < 3) {
            float h = hs[s];
            float npx = bpx + h*cvx, npy = bpy + h*cvy, npz = bpz + h*cvz;
            cvx = bvx + h*dvx; cvy = bvy + h*dvy; cvz = bvz + h*dvz;
            cpx = npx; cpy = npy; cpz = npz;
            float qw = brw + h*dqw, qx = brx + h*dqx, qy = bry + h*dqy, qz = brz + h*dqz;
            float iqn = 1.0f / fmaxf(sqrtf(qw*qw+qx*qx+qy*qy+qz*qz), 1e-12f);
            crw = qw*iqn; crx = qx*iqn; cry = qy*iqn; crz = qz*iqn;
            cox = box + h*dwx; coy = boy + h*dwy; coz = boz + h*dwz;
        }
    }

    if (q == 0) {
        const float s6 = DT / 6.0f;
        float* ob = out + (size_t)b * 13313;
        ob[      i*3+0] = bpx + s6*apx;  ob[      i*3+1] = bpy + s6*apy;  ob[      i*3+2] = bpz + s6*apz;
        ob[192 + i*3+0] = bvx + s6*avx;  ob[192 + i*3+1] = bvy + s6*avy;  ob[192 + i*3+2] = bvz + s6*avz;
        {
            float qw=brw+s6*arw, qx=brx+s6*arx, qy=bry+s6*ary, qz=brz+s6*arz;
            float iq = 1.0f / fmaxf(sqrtf(qw*qw+qx*qx+qy*qy+qz*qz), 1e-12f);
            ob[384 + i*4+0]=qw*iq; ob[384 + i*4+1]=qx*iq; ob[384 + i*4+2]=qy*iq; ob[384 + i*4+3]=qz*iq;
        }
        ob[640 + i*3+0] = box + s6*awx;  ob[640 + i*3+1] = boy + s6*awy;  ob[640 + i*3+2] = boz + s6*awz;
        ob[832 + i*3+0] = Fex + m*k1vx;  ob[832 + i*3+1] = Fey + m*k1vy;  ob[832 + i*3+2] = Fez + m*k1vz;
        if (i == 0) ob[1024] = energy[b] + s6*eacc;
    }
    #undef SF
}

// ---------------------------------------------------------------------------
// Kernel B: in-place planar->interleaved permute of out's fluid region.
// 512 blocks x 256 threads, one block per batch. Thread t's 48 loads at
// [c*4096 + z*256 + t] are EXACTLY the values it writes at [3*(z*256+t)+c]
// (same residue class mod 256) -> pure register pass-through. The single
// __syncthreads (which drains each wave's vmcnt before the barrier) makes
// the in-place overwrite safe: all block loads complete before any store.
// ---------------------------------------------------------------------------
__global__ __launch_bounds__(256) void fluid_permute(float* __restrict__ out)
{
    const int t = threadIdx.x;
    const int b = blockIdx.x;
    float* fb = out + (size_t)b*13313 + 1025;

    float v[3][16];
    #pragma unroll
    for (int c = 0; c < 3; ++c)
        #pragma unroll
        for (int z = 0; z < 16; ++z)
            v[c][z] = fb[c*4096 + z*256 + t];

    __syncthreads();    // all loads in the block landed; in-place write safe

    #pragma unroll
    for (int z = 0; z < 16; ++z) {
        float* p = fb + 3*(z*256 + t);
        p[0] = v[0][z];
        p[1] = v[1][z];
        p[2] = v[2][z];
    }
}

extern "C" void kernel_launch(void* const* d_in, const int* in_sizes, int n_in,
                              void* d_out, int out_size, void* d_ws, size_t ws_size,
                              hipStream_t stream) {
    const float* pos      = (const float*)d_in[0];
    const float* vel      = (const float*)d_in[1];
    const float* rot      = (const float*)d_in[2];
    const float* omega    = (const float*)d_in[3];
    const float* mass     = (const float*)d_in[4];
    const float* inertia  = (const float*)d_in[5];
    const float* contacts = (const float*)d_in[6];
    const float* energy   = (const float*)d_in[7];
    const float* fluid_v  = (const float*)d_in[8];
    const float* Fext     = (const float*)d_in[9];
    const float* tau      = (const float*)d_in[10];
    const float* log_A    = (const float*)d_in[11];
    const float* log_k    = (const float*)d_in[12];
    const float* log_b    = (const float*)d_in[13];
    const float* conv_w   = (const float*)d_in[14];
    float* out = (float*)d_out;

    fused_kernel<<<dim3(1024), dim3(256), 0, stream>>>(
        pos, vel, rot, omega, mass, inertia, contacts, energy, fluid_v,
        Fext, tau, log_A, log_k, log_b, conv_w, out);
    fluid_permute<<<dim3(512), dim3(256), 0, stream>>>(out);
}